// Round 1
// baseline (4223.846 us; speedup 1.0000x reference)
//
#include <hip/hip_runtime.h>
#include <math.h>

#define S_LEN 2048
#define B_SZ 2
#define NHEAD 16
#define HDIM 64
#define H_DIM 1024
#define M_ROWS (S_LEN * B_SZ)   // 4096
#define LN_EPS 1e-5f

// ---------------- LayerNorm: one block (256 thr) per row of H=1024 ----------
__global__ __launch_bounds__(256) void ln_kernel(const float* __restrict__ x,
                                                 const float* __restrict__ w,
                                                 const float* __restrict__ b,
                                                 float* __restrict__ y) {
    const int m = blockIdx.x;
    const int tid = threadIdx.x;
    const float* row = x + (size_t)m * H_DIM;
    float* out = y + (size_t)m * H_DIM;

    float4 v = ((const float4*)row)[tid];
    float s  = v.x + v.y + v.z + v.w;
    float ss = v.x * v.x + v.y * v.y + v.z * v.z + v.w * v.w;

    __shared__ float rs[4], rss[4], stats[2];
    const int wave = tid >> 6, lane = tid & 63;
    for (int off = 32; off; off >>= 1) {
        s  += __shfl_down(s, off);
        ss += __shfl_down(ss, off);
    }
    if (lane == 0) { rs[wave] = s; rss[wave] = ss; }
    __syncthreads();
    if (tid == 0) {
        float S = rs[0] + rs[1] + rs[2] + rs[3];
        float SS = rss[0] + rss[1] + rss[2] + rss[3];
        float mean = S * (1.0f / H_DIM);
        float var = SS * (1.0f / H_DIM) - mean * mean;
        stats[0] = mean;
        stats[1] = rsqrtf(var + LN_EPS);
    }
    __syncthreads();
    const float mean = stats[0], inv = stats[1];
    float4 wv = ((const float4*)w)[tid];
    float4 bv = ((const float4*)b)[tid];
    float4 o;
    o.x = (v.x - mean) * inv * wv.x + bv.x;
    o.y = (v.y - mean) * inv * wv.y + bv.y;
    o.z = (v.z - mean) * inv * wv.z + bv.z;
    o.w = (v.w - mean) * inv * wv.w + bv.w;
    ((float4*)out)[tid] = o;
}

// ---------------- GEMM: C[M,N] = A[M,K] @ B[N,K]^T + bias (+epilogue) -------
// EPI: 0 = bias, 1 = bias + residual add, 2 = bias + gelu(tanh)
template <int EPI>
__global__ __launch_bounds__(256) void gemm_bt(const float* __restrict__ A,
                                               const float* __restrict__ Bm,
                                               const float* __restrict__ bias,
                                               const float* __restrict__ resid,
                                               float* __restrict__ C,
                                               int M, int N, int K) {
    __shared__ float As[16][64];
    __shared__ float Bs[16][64];

    const int m0 = blockIdx.y * 64;
    const int n0 = blockIdx.x * 64;
    const int tx = threadIdx.x & 15;   // 0..15 -> 4 cols each
    const int ty = threadIdx.x >> 4;   // 0..15 -> 4 rows each
    const int lrow = threadIdx.x >> 2;       // 0..63: tile row for loading
    const int lk4  = (threadIdx.x & 3) << 2; // 0,4,8,12: k sub-offset

    const float* Aptr = A + (size_t)(m0 + lrow) * K + lk4;
    const float* Bptr = Bm + (size_t)(n0 + lrow) * K + lk4;

    float acc[4][4] = {};

    for (int kt = 0; kt < K; kt += 16) {
        float4 av = *(const float4*)(Aptr + kt);
        float4 bv = *(const float4*)(Bptr + kt);
        __syncthreads();
        As[lk4 + 0][lrow] = av.x; As[lk4 + 1][lrow] = av.y;
        As[lk4 + 2][lrow] = av.z; As[lk4 + 3][lrow] = av.w;
        Bs[lk4 + 0][lrow] = bv.x; Bs[lk4 + 1][lrow] = bv.y;
        Bs[lk4 + 2][lrow] = bv.z; Bs[lk4 + 3][lrow] = bv.w;
        __syncthreads();
#pragma unroll
        for (int k = 0; k < 16; k++) {
            float a[4], bb[4];
#pragma unroll
            for (int i = 0; i < 4; i++) a[i] = As[k][ty * 4 + i];
#pragma unroll
            for (int j = 0; j < 4; j++) bb[j] = Bs[k][tx * 4 + j];
#pragma unroll
            for (int i = 0; i < 4; i++)
#pragma unroll
                for (int j = 0; j < 4; j++) acc[i][j] += a[i] * bb[j];
        }
    }

#pragma unroll
    for (int i = 0; i < 4; i++) {
        const int row = m0 + ty * 4 + i;
#pragma unroll
        for (int j = 0; j < 4; j++) {
            const int col = n0 + tx * 4 + j;
            float vv = acc[i][j] + bias[col];
            if (EPI == 1) vv += resid[(size_t)row * N + col];
            if (EPI == 2) {
                const float t = vv;
                vv = 0.5f * t * (1.0f + tanhf(0.7978845608f * (t + 0.044715f * t * t * t)));
            }
            C[(size_t)row * N + col] = vv;
        }
    }
}

// ---------------- causal attention: one 64-thread block per (s, b, nh) ------
// qkv layout: [m = s*B+b][3H] with channel nh*192 + comp*64 + d (comp: q/k/v)
// out layout: [m][nh*64 + d]
__global__ __launch_bounds__(64) void attn_kernel(const float* __restrict__ qkv,
                                                  float* __restrict__ out) {
    const int s = blockIdx.x;
    const int b = blockIdx.y / NHEAD;
    const int nh = blockIdx.y % NHEAD;
    const int tid = threadIdx.x;

    __shared__ float sc[S_LEN];
    __shared__ float qs[HDIM];
    __shared__ float red[2];

    const size_t row_stride = (size_t)B_SZ * 3 * H_DIM; // stride between s steps for fixed b
    const float* qrow = qkv + ((size_t)(s * B_SZ + b)) * 3 * H_DIM + nh * 3 * HDIM;
    qs[tid] = qrow[tid] * 0.125f;   // 1/sqrt(64)
    __syncthreads();

    // pass 1: scores
    float lmax = -INFINITY;
    const float* kbase = qkv + (size_t)b * 3 * H_DIM + nh * 3 * HDIM + HDIM;
    for (int t = tid; t <= s; t += 64) {
        const float* krow = kbase + (size_t)t * row_stride;
        float d = 0.0f;
#pragma unroll
        for (int c = 0; c < 16; c++) {
            float4 kv = ((const float4*)krow)[c];
            float4 qv = ((const float4*)qs)[c];
            d += kv.x * qv.x + kv.y * qv.y + kv.z * qv.z + kv.w * qv.w;
        }
        sc[t] = d;
        lmax = fmaxf(lmax, d);
    }
    for (int off = 32; off; off >>= 1) lmax = fmaxf(lmax, __shfl_down(lmax, off));
    if (tid == 0) red[0] = lmax;
    __syncthreads();
    const float mx = red[0];

    float lsum = 0.0f;
    for (int t = tid; t <= s; t += 64) {
        const float p = __expf(sc[t] - mx);
        sc[t] = p;
        lsum += p;
    }
    for (int off = 32; off; off >>= 1) lsum += __shfl_down(lsum, off);
    if (tid == 0) red[1] = lsum;
    __syncthreads();
    const float inv = 1.0f / red[1];

    // pass 2: O[d] = sum_t p[t] * V[t][d]; thread == d, coalesced over V rows
    float o = 0.0f;
    const float* vbase = qkv + (size_t)b * 3 * H_DIM + nh * 3 * HDIM + 2 * HDIM + tid;
#pragma unroll 4
    for (int t = 0; t <= s; t++) {
        o += sc[t] * vbase[(size_t)t * row_stride];
    }
    out[((size_t)(s * B_SZ + b)) * H_DIM + nh * HDIM + tid] = o * inv;
}

extern "C" void kernel_launch(void* const* d_in, const int* in_sizes, int n_in,
                              void* d_out, int out_size, void* d_ws, size_t ws_size,
                              hipStream_t stream) {
    const float* x      = (const float*)d_in[0];
    const float* ln1_w  = (const float*)d_in[1];
    const float* ln1_b  = (const float*)d_in[2];
    const float* w_qkv  = (const float*)d_in[3];
    const float* b_qkv  = (const float*)d_in[4];
    const float* w_proj = (const float*)d_in[5];
    const float* b_proj = (const float*)d_in[6];
    const float* ln2_w  = (const float*)d_in[7];
    const float* ln2_b  = (const float*)d_in[8];
    const float* w_fc1  = (const float*)d_in[9];
    const float* b_fc1  = (const float*)d_in[10];
    const float* w_fc2  = (const float*)d_in[11];
    const float* b_fc2  = (const float*)d_in[12];
    float* out = (float*)d_out;

    char* ws = (char*)d_ws;
    float* ln_buf   = (float*)(ws);                      // 16 MB [M,H]
    float* attn_buf = (float*)(ws + (size_t)(16 << 20)); // 16 MB [M,H]
    float* qkv_buf  = (float*)(ws + (size_t)(32 << 20)); // 48 MB [M,3H]
    float* fc1_buf  = (float*)(ws + (size_t)(16 << 20)); // 64 MB [M,4H] (attn+qkv dead)

    // 1) LN1
    ln_kernel<<<M_ROWS, 256, 0, stream>>>(x, ln1_w, ln1_b, ln_buf);

    // 2) QKV = ln1 @ w_qkv^T + b_qkv          [4096, 3072]
    gemm_bt<0><<<dim3(3072 / 64, M_ROWS / 64), 256, 0, stream>>>(
        ln_buf, w_qkv, b_qkv, nullptr, qkv_buf, M_ROWS, 3 * H_DIM, H_DIM);

    // 3) causal attention                      [4096, 1024]
    attn_kernel<<<dim3(S_LEN, B_SZ * NHEAD), 64, 0, stream>>>(qkv_buf, attn_buf);

    // 4) x1 = x + attn @ w_proj^T + b_proj  -> d_out
    gemm_bt<1><<<dim3(H_DIM / 64, M_ROWS / 64), 256, 0, stream>>>(
        attn_buf, w_proj, b_proj, x, out, M_ROWS, H_DIM, H_DIM);

    // 5) LN2 on x1
    ln_kernel<<<M_ROWS, 256, 0, stream>>>(out, ln2_w, ln2_b, ln_buf);

    // 6) fc1 + gelu                           [4096, 4096]
    gemm_bt<2><<<dim3(4096 / 64, M_ROWS / 64), 256, 0, stream>>>(
        ln_buf, w_fc1, b_fc1, nullptr, fc1_buf, M_ROWS, 4 * H_DIM, H_DIM);

    // 7) out = x1 + fc1 @ w_fc2^T + b_fc2   (in-place residual from d_out)
    gemm_bt<1><<<dim3(H_DIM / 64, M_ROWS / 64), 256, 0, stream>>>(
        fc1_buf, w_fc2, b_fc2, out, out, M_ROWS, H_DIM, 4 * H_DIM);
}

// Round 2
// 1105.404 us; speedup vs baseline: 3.8211x; 3.8211x over previous
//
#include <hip/hip_runtime.h>
#include <math.h>

#define S_LEN 2048
#define B_SZ 2
#define NHEAD 16
#define HDIM 64
#define H_DIM 1024
#define M_ROWS (S_LEN * B_SZ)   // 4096
#define LN_EPS 1e-5f
#define APAD 68

typedef __attribute__((ext_vector_type(4))) float f32x4;
typedef __attribute__((ext_vector_type(8))) short short8;
typedef __attribute__((ext_vector_type(8))) unsigned short u16x8;
typedef __attribute__((ext_vector_type(4))) unsigned short u16x4;

__device__ __forceinline__ float bf2f(unsigned short u) {
    return __uint_as_float(((unsigned int)u) << 16);
}
__device__ __forceinline__ unsigned short f2bf(float f) {
    unsigned int u = __float_as_uint(f);
    return (unsigned short)((u + 0x7fffu + ((u >> 16) & 1u)) >> 16);
}
__device__ __forceinline__ void gld_lds16(const void* g, void* l) {
    __builtin_amdgcn_global_load_lds(
        (const __attribute__((address_space(1))) void*)g,
        (__attribute__((address_space(3))) void*)l, 16, 0, 0);
}

// ---------------- weight cast fp32 -> bf16 ----------------------------------
__global__ __launch_bounds__(256) void cast_w(const float* __restrict__ in,
                                              unsigned short* __restrict__ out,
                                              int n4) {
    const int i = blockIdx.x * 256 + threadIdx.x;
    if (i < n4) {
        f32x4 v = ((const f32x4*)in)[i];
        u16x4 o;
        o.x = f2bf(v.x); o.y = f2bf(v.y); o.z = f2bf(v.z); o.w = f2bf(v.w);
        ((u16x4*)out)[i] = o;
    }
}

// ---------------- LayerNorm row of 1024 -> bf16 -----------------------------
__global__ __launch_bounds__(256) void ln_bf16(const float* __restrict__ x,
                                               const float* __restrict__ w,
                                               const float* __restrict__ b,
                                               unsigned short* __restrict__ y) {
    const int m = blockIdx.x;
    const int tid = threadIdx.x;
    const float* row = x + (size_t)m * H_DIM;

    float4 v = ((const float4*)row)[tid];
    float s  = v.x + v.y + v.z + v.w;
    float ss = v.x * v.x + v.y * v.y + v.z * v.z + v.w * v.w;

    __shared__ float rs[4], rss[4], stats[2];
    const int wave = tid >> 6, lane = tid & 63;
    for (int off = 32; off; off >>= 1) {
        s  += __shfl_down(s, off);
        ss += __shfl_down(ss, off);
    }
    if (lane == 0) { rs[wave] = s; rss[wave] = ss; }
    __syncthreads();
    if (tid == 0) {
        float S = rs[0] + rs[1] + rs[2] + rs[3];
        float SS = rss[0] + rss[1] + rss[2] + rss[3];
        float mean = S * (1.0f / H_DIM);
        float var = SS * (1.0f / H_DIM) - mean * mean;
        stats[0] = mean;
        stats[1] = rsqrtf(var + LN_EPS);
    }
    __syncthreads();
    const float mean = stats[0], inv = stats[1];
    float4 wv = ((const float4*)w)[tid];
    float4 bv = ((const float4*)b)[tid];
    u16x4 o;
    o.x = f2bf((v.x - mean) * inv * wv.x + bv.x);
    o.y = f2bf((v.y - mean) * inv * wv.y + bv.y);
    o.z = f2bf((v.z - mean) * inv * wv.z + bv.z);
    o.w = f2bf((v.w - mean) * inv * wv.w + bv.w);
    ((u16x4*)(y + (size_t)m * H_DIM))[tid] = o;
}

// ---------------- bf16 MFMA GEMM: C[M,N] = A[M,K] @ B[N,K]^T + bias ---------
// EPI: 0 = bias, 1 = bias + residual, 2 = bias + gelu(tanh). BF_OUT: bf16 C.
template <int EPI, bool BF_OUT>
__global__ __launch_bounds__(256) void gemm_mfma(const unsigned short* __restrict__ A,
                                                 const unsigned short* __restrict__ B,
                                                 const float* __restrict__ bias,
                                                 const float* __restrict__ resid,
                                                 void* __restrict__ Cout,
                                                 int M, int N, int K) {
    __shared__ __attribute__((aligned(16))) unsigned short As[128 * 32];
    __shared__ __attribute__((aligned(16))) unsigned short Bs[128 * 32];

    const int tid = threadIdx.x;
    const int wid = tid >> 6;
    const int ln  = tid & 63;
    const int quad = ln >> 4;
    const int mr   = ln & 15;
    const int wm = (wid >> 1) * 64;
    const int wn = (wid & 1) * 64;
    const int m0 = blockIdx.y * 128;
    const int n0 = blockIdx.x * 128;

    // staging: chunk c covers LDS bytes [c*16, c*16+16) = row c>>2, k (c&3)*8
    const int c  = wid * 64 + ln;
    const int r0 = c >> 2;
    const int k0 = (c & 3) * 8;
    const unsigned short* gA0 = A + (size_t)(m0 + r0) * K + k0;
    const unsigned short* gA1 = A + (size_t)(m0 + 64 + r0) * K + k0;
    const unsigned short* gB0 = B + (size_t)(n0 + r0) * K + k0;
    const unsigned short* gB1 = B + (size_t)(n0 + 64 + r0) * K + k0;
    unsigned short* lA0 = As + wid * 512;
    unsigned short* lA1 = As + 2048 + wid * 512;
    unsigned short* lB0 = Bs + wid * 512;
    unsigned short* lB1 = Bs + 2048 + wid * 512;

    const f32x4 zero = {0.f, 0.f, 0.f, 0.f};
    f32x4 acc[4][4];
#pragma unroll
    for (int i = 0; i < 4; i++)
#pragma unroll
        for (int j = 0; j < 4; j++) acc[i][j] = zero;

    for (int kt = 0; kt < K; kt += 32) {
        __syncthreads();
        gld_lds16(gA0 + kt, lA0);
        gld_lds16(gA1 + kt, lA1);
        gld_lds16(gB0 + kt, lB0);
        gld_lds16(gB1 + kt, lB1);
        __syncthreads();
        short8 af[4], bfr[4];
#pragma unroll
        for (int i = 0; i < 4; i++)
            af[i] = *(const short8*)(As + (wm + i * 16 + mr) * 32 + quad * 8);
#pragma unroll
        for (int j = 0; j < 4; j++)
            bfr[j] = *(const short8*)(Bs + (wn + j * 16 + mr) * 32 + quad * 8);
#pragma unroll
        for (int i = 0; i < 4; i++)
#pragma unroll
            for (int j = 0; j < 4; j++)
                acc[i][j] = __builtin_amdgcn_mfma_f32_16x16x32_bf16(af[i], bfr[j], acc[i][j], 0, 0, 0);
    }

#pragma unroll
    for (int j = 0; j < 4; j++) {
        const int n = n0 + wn + j * 16 + mr;
        const float bv = bias[n];
#pragma unroll
        for (int i = 0; i < 4; i++) {
#pragma unroll
            for (int r = 0; r < 4; r++) {
                const int m = m0 + wm + i * 16 + quad * 4 + r;
                float v = acc[i][j][r] + bv;
                if (EPI == 1) v += resid[(size_t)m * N + n];
                if (EPI == 2) {
                    const float t = v;
                    v = 0.5f * t * (1.0f + tanhf(0.7978845608f * (t + 0.044715f * t * t * t)));
                }
                if (BF_OUT) ((unsigned short*)Cout)[(size_t)m * N + n] = f2bf(v);
                else        ((float*)Cout)[(size_t)m * N + n] = v;
            }
        }
    }
}

// ---------------- flash attention: block = 64-query tile x (b,nh) -----------
// qkv bf16 [m=s*2+b][3072], channel nh*192 + comp*64 + d; out bf16 [m][nh*64+d]
__global__ __launch_bounds__(256) void attn_flash(const unsigned short* __restrict__ qkv,
                                                  unsigned short* __restrict__ out) {
    __shared__ __attribute__((aligned(16))) float Qs[64 * APAD];  // [r][d]
    __shared__ __attribute__((aligned(16))) float KP[64 * APAD];  // K:[c][d] then P:[r][t]
    __shared__ __attribute__((aligned(16))) float Vs[64 * APAD];  // [d][t]

    const int tid = threadIdx.x;
    const int qt = blockIdx.x;
    const int q0 = qt * 64;
    const int b  = blockIdx.y >> 4;
    const int nh = blockIdx.y & 15;
    const int tx = tid & 15, ty = tid >> 4;
    const int sr = tid >> 2, sc = tid & 3;

    const size_t chanQ = (size_t)nh * 192;

    // stage Q (scaled by 1/sqrt(64))
    {
        const unsigned short* gq = qkv + (size_t)((q0 + sr) * 2 + b) * 3072 + chanQ + sc * 16;
        u16x8 h0 = *(const u16x8*)gq;
        u16x8 h1 = *(const u16x8*)(gq + 8);
        float* dst = Qs + sr * APAD + sc * 16;
#pragma unroll
        for (int jj = 0; jj < 8; jj++) dst[jj] = bf2f(h0[jj]) * 0.125f;
#pragma unroll
        for (int jj = 0; jj < 8; jj++) dst[8 + jj] = bf2f(h1[jj]) * 0.125f;
    }

    float o[4][4];
    float mo[4], lo[4];
#pragma unroll
    for (int i = 0; i < 4; i++) {
        mo[i] = -1e30f; lo[i] = 0.f;
#pragma unroll
        for (int j = 0; j < 4; j++) o[i][j] = 0.f;
    }

    for (int kt = 0; kt <= qt; kt++) {
        __syncthreads();   // prior PV reads done (and Q staged on first iter)
        {
            const unsigned short* gk =
                qkv + (size_t)((kt * 64 + sr) * 2 + b) * 3072 + chanQ + 64 + sc * 16;
            u16x8 h0 = *(const u16x8*)gk;
            u16x8 h1 = *(const u16x8*)(gk + 8);
            float* dk = KP + sr * APAD + sc * 16;
#pragma unroll
            for (int jj = 0; jj < 8; jj++) dk[jj] = bf2f(h0[jj]);
#pragma unroll
            for (int jj = 0; jj < 8; jj++) dk[8 + jj] = bf2f(h1[jj]);
            u16x8 v0 = *(const u16x8*)(gk + 64);
            u16x8 v1 = *(const u16x8*)(gk + 72);
#pragma unroll
            for (int jj = 0; jj < 8; jj++) Vs[(sc * 16 + jj) * APAD + sr] = bf2f(v0[jj]);
#pragma unroll
            for (int jj = 0; jj < 8; jj++) Vs[(sc * 16 + 8 + jj) * APAD + sr] = bf2f(v1[jj]);
        }
        __syncthreads();   // K,V staged

        // S = Q K^T  (rows 4ty+i, cols 4tx+j)
        float p[4][4];
#pragma unroll
        for (int i = 0; i < 4; i++)
#pragma unroll
            for (int j = 0; j < 4; j++) p[i][j] = 0.f;
#pragma unroll 4
        for (int d4 = 0; d4 < 16; d4++) {
            f32x4 a[4], bb[4];
#pragma unroll
            for (int i = 0; i < 4; i++) a[i] = *(const f32x4*)(Qs + (4 * ty + i) * APAD + d4 * 4);
#pragma unroll
            for (int j = 0; j < 4; j++) bb[j] = *(const f32x4*)(KP + (4 * tx + j) * APAD + d4 * 4);
#pragma unroll
            for (int i = 0; i < 4; i++)
#pragma unroll
                for (int j = 0; j < 4; j++) {
                    p[i][j] += a[i].x * bb[j].x;
                    p[i][j] += a[i].y * bb[j].y;
                    p[i][j] += a[i].z * bb[j].z;
                    p[i][j] += a[i].w * bb[j].w;
                }
        }
        if (kt == qt) {
#pragma unroll
            for (int i = 0; i < 4; i++)
#pragma unroll
                for (int j = 0; j < 4; j++)
                    if (4 * tx + j > 4 * ty + i) p[i][j] = -1e30f;
        }

        // row max across j and the 16-lane tx group
        float rm[4];
#pragma unroll
        for (int i = 0; i < 4; i++) {
            rm[i] = fmaxf(fmaxf(p[i][0], p[i][1]), fmaxf(p[i][2], p[i][3]));
            rm[i] = fmaxf(rm[i], __shfl_xor(rm[i], 1));
            rm[i] = fmaxf(rm[i], __shfl_xor(rm[i], 2));
            rm[i] = fmaxf(rm[i], __shfl_xor(rm[i], 4));
            rm[i] = fmaxf(rm[i], __shfl_xor(rm[i], 8));
        }

        __syncthreads();   // all QK reads of KP done before P overwrites it

        float al[4];
#pragma unroll
        for (int i = 0; i < 4; i++) {
            const float mn = fmaxf(mo[i], rm[i]);
            al[i] = __expf(mo[i] - mn);
            mo[i] = mn;
            float s = 0.f;
#pragma unroll
            for (int j = 0; j < 4; j++) {
                p[i][j] = __expf(p[i][j] - mn);
                s += p[i][j];
            }
            s += __shfl_xor(s, 1);
            s += __shfl_xor(s, 2);
            s += __shfl_xor(s, 4);
            s += __shfl_xor(s, 8);
            lo[i] = lo[i] * al[i] + s;
#pragma unroll
            for (int j = 0; j < 4; j++) {
                o[i][j] *= al[i];
                KP[(4 * ty + i) * APAD + 4 * tx + j] = p[i][j];
            }
        }
        __syncthreads();   // P visible

        // O += P V   (o[i][j]: row 4ty+i, dim 4tx+j)
#pragma unroll 4
        for (int t4 = 0; t4 < 16; t4++) {
            f32x4 a[4], bb[4];
#pragma unroll
            for (int i = 0; i < 4; i++) a[i] = *(const f32x4*)(KP + (4 * ty + i) * APAD + t4 * 4);
#pragma unroll
            for (int j = 0; j < 4; j++) bb[j] = *(const f32x4*)(Vs + (4 * tx + j) * APAD + t4 * 4);
#pragma unroll
            for (int i = 0; i < 4; i++)
#pragma unroll
                for (int j = 0; j < 4; j++) {
                    o[i][j] += a[i].x * bb[j].x;
                    o[i][j] += a[i].y * bb[j].y;
                    o[i][j] += a[i].z * bb[j].z;
                    o[i][j] += a[i].w * bb[j].w;
                }
        }
    }

#pragma unroll
    for (int i = 0; i < 4; i++) {
        const float inv = 1.0f / lo[i];
        const int m = (q0 + 4 * ty + i) * 2 + b;
        u16x4 pk;
        pk.x = f2bf(o[i][0] * inv);
        pk.y = f2bf(o[i][1] * inv);
        pk.z = f2bf(o[i][2] * inv);
        pk.w = f2bf(o[i][3] * inv);
        *(u16x4*)(out + (size_t)m * H_DIM + nh * HDIM + 4 * tx) = pk;
    }
}

extern "C" void kernel_launch(void* const* d_in, const int* in_sizes, int n_in,
                              void* d_out, int out_size, void* d_ws, size_t ws_size,
                              hipStream_t stream) {
    const float* x      = (const float*)d_in[0];
    const float* ln1_w  = (const float*)d_in[1];
    const float* ln1_b  = (const float*)d_in[2];
    const float* w_qkv  = (const float*)d_in[3];
    const float* b_qkv  = (const float*)d_in[4];
    const float* w_proj = (const float*)d_in[5];
    const float* b_proj = (const float*)d_in[6];
    const float* ln2_w  = (const float*)d_in[7];
    const float* ln2_b  = (const float*)d_in[8];
    const float* w_fc1  = (const float*)d_in[9];
    const float* b_fc1  = (const float*)d_in[10];
    const float* w_fc2  = (const float*)d_in[11];
    const float* b_fc2  = (const float*)d_in[12];
    float* out = (float*)d_out;

    char* ws = (char*)d_ws;
    unsigned short* wqkv_bf  = (unsigned short*)(ws);                        // 6 MB
    unsigned short* wproj_bf = (unsigned short*)(ws + ((size_t)6 << 20));    // 2 MB
    unsigned short* wfc1_bf  = (unsigned short*)(ws + ((size_t)8 << 20));    // 8 MB
    unsigned short* wfc2_bf  = (unsigned short*)(ws + ((size_t)16 << 20));   // 8 MB
    unsigned short* ln_buf   = (unsigned short*)(ws + ((size_t)24 << 20));   // 8 MB
    unsigned short* qkv_bf   = (unsigned short*)(ws + ((size_t)32 << 20));   // 24 MB
    unsigned short* attn_bf  = (unsigned short*)(ws + ((size_t)56 << 20));   // 8 MB
    unsigned short* fc1_bf   = (unsigned short*)(ws + ((size_t)32 << 20));   // 32 MB (qkv/attn dead)

    // weight casts (per-launch; graph-safe)
    cast_w<<<3072, 256, 0, stream>>>(w_qkv,  wqkv_bf,  3 * 1024 * 1024 / 4);
    cast_w<<<1024, 256, 0, stream>>>(w_proj, wproj_bf, 1024 * 1024 / 4);
    cast_w<<<4096, 256, 0, stream>>>(w_fc1,  wfc1_bf,  4 * 1024 * 1024 / 4);
    cast_w<<<4096, 256, 0, stream>>>(w_fc2,  wfc2_bf,  4 * 1024 * 1024 / 4);

    // 1) LN1 -> bf16
    ln_bf16<<<M_ROWS, 256, 0, stream>>>(x, ln1_w, ln1_b, ln_buf);
    // 2) qkv = ln1 @ w_qkv^T + b_qkv   [4096,3072] bf16
    gemm_mfma<0, true><<<dim3(24, 32), 256, 0, stream>>>(
        ln_buf, wqkv_bf, b_qkv, nullptr, qkv_bf, M_ROWS, 3072, 1024);
    // 3) flash attention -> bf16 [4096,1024]
    attn_flash<<<dim3(32, 32), 256, 0, stream>>>(qkv_bf, attn_bf);
    // 4) x1 = x + attn @ w_proj^T + b_proj  -> d_out (fp32)
    gemm_mfma<1, false><<<dim3(8, 32), 256, 0, stream>>>(
        attn_bf, wproj_bf, b_proj, x, out, M_ROWS, 1024, 1024);
    // 5) LN2 -> bf16
    ln_bf16<<<M_ROWS, 256, 0, stream>>>(out, ln2_w, ln2_b, ln_buf);
    // 6) fc1 + gelu -> bf16 [4096,4096]
    gemm_mfma<2, true><<<dim3(32, 32), 256, 0, stream>>>(
        ln_buf, wfc1_bf, b_fc1, nullptr, fc1_bf, M_ROWS, 4096, 1024);
    // 7) out = x1 + fc1 @ w_fc2^T + b_fc2 (in-place residual)
    gemm_mfma<1, false><<<dim3(8, 32), 256, 0, stream>>>(
        fc1_bf, wfc2_bf, b_fc2, out, out, M_ROWS, 1024, 4096);
}

// Round 3
// 445.848 us; speedup vs baseline: 9.4737x; 2.4793x over previous
//
#include <hip/hip_runtime.h>
#include <math.h>

#define S_LEN 2048
#define B_SZ 2
#define NHEAD 16
#define HDIM 64
#define H_DIM 1024
#define M_ROWS (S_LEN * B_SZ)   // 4096
#define LN_EPS 1e-5f
#define KSTR 72                  // LDS row stride (shorts): 36 words -> 2-way banks = free

typedef __attribute__((ext_vector_type(4))) float f32x4;
typedef __attribute__((ext_vector_type(8))) short short8;
typedef __attribute__((ext_vector_type(8))) unsigned short u16x8;
typedef __attribute__((ext_vector_type(4))) unsigned short u16x4;
typedef __attribute__((ext_vector_type(2))) unsigned short u16x2;

__device__ __forceinline__ float bf2f(unsigned short u) {
    return __uint_as_float(((unsigned int)u) << 16);
}
__device__ __forceinline__ unsigned short f2bf(float f) {
    unsigned int u = __float_as_uint(f);
    return (unsigned short)((u + 0x7fffu + ((u >> 16) & 1u)) >> 16);
}
__device__ __forceinline__ void gld_lds16(const void* g, void* l) {
    __builtin_amdgcn_global_load_lds(
        (const __attribute__((address_space(1))) void*)g,
        (__attribute__((address_space(3))) void*)l, 16, 0, 0);
}

// ---------------- weight cast fp32 -> bf16 ----------------------------------
__global__ __launch_bounds__(256) void cast_w(const float* __restrict__ in,
                                              unsigned short* __restrict__ out,
                                              int n4) {
    const int i = blockIdx.x * 256 + threadIdx.x;
    if (i < n4) {
        f32x4 v = ((const f32x4*)in)[i];
        u16x4 o;
        o.x = f2bf(v.x); o.y = f2bf(v.y); o.z = f2bf(v.z); o.w = f2bf(v.w);
        ((u16x4*)out)[i] = o;
    }
}

// ---------------- LayerNorm row of 1024 -> bf16 -----------------------------
__global__ __launch_bounds__(256) void ln_bf16(const float* __restrict__ x,
                                               const float* __restrict__ w,
                                               const float* __restrict__ b,
                                               unsigned short* __restrict__ y) {
    const int m = blockIdx.x;
    const int tid = threadIdx.x;
    const float* row = x + (size_t)m * H_DIM;

    float4 v = ((const float4*)row)[tid];
    float s  = v.x + v.y + v.z + v.w;
    float ss = v.x * v.x + v.y * v.y + v.z * v.z + v.w * v.w;

    __shared__ float rs[4], rss[4], stats[2];
    const int wave = tid >> 6, lane = tid & 63;
    for (int off = 32; off; off >>= 1) {
        s  += __shfl_down(s, off);
        ss += __shfl_down(ss, off);
    }
    if (lane == 0) { rs[wave] = s; rss[wave] = ss; }
    __syncthreads();
    if (tid == 0) {
        float S = rs[0] + rs[1] + rs[2] + rs[3];
        float SS = rss[0] + rss[1] + rss[2] + rss[3];
        float mean = S * (1.0f / H_DIM);
        float var = SS * (1.0f / H_DIM) - mean * mean;
        stats[0] = mean;
        stats[1] = rsqrtf(var + LN_EPS);
    }
    __syncthreads();
    const float mean = stats[0], inv = stats[1];
    float4 wv = ((const float4*)w)[tid];
    float4 bv = ((const float4*)b)[tid];
    u16x4 o;
    o.x = f2bf((v.x - mean) * inv * wv.x + bv.x);
    o.y = f2bf((v.y - mean) * inv * wv.y + bv.y);
    o.z = f2bf((v.z - mean) * inv * wv.z + bv.z);
    o.w = f2bf((v.w - mean) * inv * wv.w + bv.w);
    ((u16x4*)(y + (size_t)m * H_DIM))[tid] = o;
}

// ---------------- bf16 MFMA GEMM: C[M,N] = A[M,K] @ B[N,K]^T + bias ---------
// EPI: 0 = bias, 1 = bias + residual, 2 = bias + gelu(tanh). BF_OUT: bf16 C.
template <int EPI, bool BF_OUT>
__global__ __launch_bounds__(256) void gemm_mfma(const unsigned short* __restrict__ A,
                                                 const unsigned short* __restrict__ B,
                                                 const float* __restrict__ bias,
                                                 const float* __restrict__ resid,
                                                 void* __restrict__ Cout,
                                                 int M, int N, int K) {
    __shared__ __attribute__((aligned(16))) unsigned short As[128 * 32];
    __shared__ __attribute__((aligned(16))) unsigned short Bs[128 * 32];

    const int tid = threadIdx.x;
    const int wid = tid >> 6;
    const int ln  = tid & 63;
    const int quad = ln >> 4;
    const int mr   = ln & 15;
    const int wm = (wid >> 1) * 64;
    const int wn = (wid & 1) * 64;
    const int m0 = blockIdx.y * 128;
    const int n0 = blockIdx.x * 128;

    const int c  = wid * 64 + ln;
    const int r0 = c >> 2;
    const int k0 = (c & 3) * 8;
    const unsigned short* gA0 = A + (size_t)(m0 + r0) * K + k0;
    const unsigned short* gA1 = A + (size_t)(m0 + 64 + r0) * K + k0;
    const unsigned short* gB0 = B + (size_t)(n0 + r0) * K + k0;
    const unsigned short* gB1 = B + (size_t)(n0 + 64 + r0) * K + k0;
    unsigned short* lA0 = As + wid * 512;
    unsigned short* lA1 = As + 2048 + wid * 512;
    unsigned short* lB0 = Bs + wid * 512;
    unsigned short* lB1 = Bs + 2048 + wid * 512;

    const f32x4 zero = {0.f, 0.f, 0.f, 0.f};
    f32x4 acc[4][4];
#pragma unroll
    for (int i = 0; i < 4; i++)
#pragma unroll
        for (int j = 0; j < 4; j++) acc[i][j] = zero;

    for (int kt = 0; kt < K; kt += 32) {
        __syncthreads();
        gld_lds16(gA0 + kt, lA0);
        gld_lds16(gA1 + kt, lA1);
        gld_lds16(gB0 + kt, lB0);
        gld_lds16(gB1 + kt, lB1);
        __syncthreads();
        short8 af[4], bfr[4];
#pragma unroll
        for (int i = 0; i < 4; i++)
            af[i] = *(const short8*)(As + (wm + i * 16 + mr) * 32 + quad * 8);
#pragma unroll
        for (int j = 0; j < 4; j++)
            bfr[j] = *(const short8*)(Bs + (wn + j * 16 + mr) * 32 + quad * 8);
#pragma unroll
        for (int i = 0; i < 4; i++)
#pragma unroll
            for (int j = 0; j < 4; j++)
                acc[i][j] = __builtin_amdgcn_mfma_f32_16x16x32_bf16(af[i], bfr[j], acc[i][j], 0, 0, 0);
    }

#pragma unroll
    for (int j = 0; j < 4; j++) {
        const int n = n0 + wn + j * 16 + mr;
        const float bv = bias[n];
#pragma unroll
        for (int i = 0; i < 4; i++) {
#pragma unroll
            for (int r = 0; r < 4; r++) {
                const int m = m0 + wm + i * 16 + quad * 4 + r;
                float v = acc[i][j][r] + bv;
                if (EPI == 1) v += resid[(size_t)m * N + n];
                if (EPI == 2) {
                    const float t = v;
                    v = 0.5f * t * (1.0f + tanhf(0.7978845608f * (t + 0.044715f * t * t * t)));
                }
                if (BF_OUT) ((unsigned short*)Cout)[(size_t)m * N + n] = f2bf(v);
                else        ((float*)Cout)[(size_t)m * N + n] = v;
            }
        }
    }
}

// ---------------- MFMA flash attention --------------------------------------
// qkv bf16 [m=s*2+b][3072], channel nh*192 + comp*64 + d; out bf16 [m][nh*64+d]
// Block = 256 thr (4 waves). Processes two 64-query tiles: qt=pa and 31-pa.
// Each wave owns a 16-row query strip. K,V^T staged in LDS (stride 72 shorts,
// 2-way banks = free). P round-trips through wave-private LDS strip.
__global__ __launch_bounds__(256) void attn_mfma(const unsigned short* __restrict__ qkv,
                                                 unsigned short* __restrict__ out) {
    __shared__ __attribute__((aligned(16))) unsigned short Ks[64 * KSTR];  // [kcol][d]
    __shared__ __attribute__((aligned(16))) unsigned short Vs[64 * KSTR];  // [d][t]
    __shared__ __attribute__((aligned(16))) unsigned short Ps[64 * KSTR];  // [q][t] per-wave strips

    const int tid = threadIdx.x;
    const int wid = tid >> 6;
    const int ln  = tid & 63;
    const int quad = ln >> 4;
    const int mr   = ln & 15;
    const int pa = blockIdx.x;                 // 0..15
    const int b  = blockIdx.y >> 4;
    const int nh = blockIdx.y & 15;
    const size_t chan = (size_t)nh * 192;

    // K staging coords: thread -> (row, 16-elem chunk)
    const int ksr = tid >> 2, ksc = tid & 3;
    // V staging coords: thread -> (t pair, 8 d)
    const int vt0 = (tid & 31) * 2, vd0 = (tid >> 5) * 8;

#pragma unroll
    for (int half = 0; half < 2; half++) {
        const int qt = half ? (31 - pa) : pa;
        const int qb = qt * 64;

        // Q fragments (A-layout), scaled later via fp32 score scale
        short8 qf0, qf1;
        {
            const int qrow = qb + wid * 16 + mr;
            const unsigned short* gq = qkv + ((size_t)(qrow * 2 + b)) * 3072 + chan + quad * 8;
            qf0 = *(const short8*)gq;
            qf1 = *(const short8*)(gq + 32);
        }

        const f32x4 zero = {0.f, 0.f, 0.f, 0.f};
        f32x4 o[4];
        float mo[4], lo[4];
#pragma unroll
        for (int d = 0; d < 4; d++) o[d] = zero;
#pragma unroll
        for (int r = 0; r < 4; r++) { mo[r] = -1e30f; lo[r] = 0.f; }

        for (int kt = 0; kt <= qt; kt++) {
            const int ktb = kt * 64;
            __syncthreads();   // prev iter's Ks/Vs reads done
            // ---- stage K [kcol][d] ----
            {
                const unsigned short* gk =
                    qkv + ((size_t)((ktb + ksr) * 2 + b)) * 3072 + chan + 64 + ksc * 16;
                u16x8 k0 = *(const u16x8*)gk;
                u16x8 k1 = *(const u16x8*)(gk + 8);
                *(u16x8*)(Ks + ksr * KSTR + ksc * 16) = k0;
                *(u16x8*)(Ks + ksr * KSTR + ksc * 16 + 8) = k1;
            }
            // ---- stage V^T [d][t] (bank = tid&31 on writes: conflict-free) ----
            {
                const unsigned short* gv =
                    qkv + ((size_t)((ktb + vt0) * 2 + b)) * 3072 + chan + 128 + vd0;
                u16x8 v0 = *(const u16x8*)gv;
                u16x8 v1 = *(const u16x8*)(gv + 6144);
#pragma unroll
                for (int j = 0; j < 8; j++) {
                    u16x2 pr; pr.x = v0[j]; pr.y = v1[j];
                    *(u16x2*)(Vs + (vd0 + j) * KSTR + vt0) = pr;
                }
            }
            __syncthreads();   // staging visible

            // ---- S = Q K^T (4 n-subtiles of 16 cols) ----
            f32x4 sacc[4];
#pragma unroll
            for (int n = 0; n < 4; n++) {
                sacc[n] = zero;
                const unsigned short* kb = Ks + (n * 16 + mr) * KSTR + quad * 8;
                short8 kfr0 = *(const short8*)kb;
                short8 kfr1 = *(const short8*)(kb + 32);
                sacc[n] = __builtin_amdgcn_mfma_f32_16x16x32_bf16(qf0, kfr0, sacc[n], 0, 0, 0);
                sacc[n] = __builtin_amdgcn_mfma_f32_16x16x32_bf16(qf1, kfr1, sacc[n], 0, 0, 0);
            }

            // ---- online softmax (rows quad*4+r, cols n*16+mr) ----
            float sv[4][4];  // [n][r]
#pragma unroll
            for (int n = 0; n < 4; n++)
#pragma unroll
                for (int r = 0; r < 4; r++) sv[n][r] = sacc[n][r] * 0.125f;
            if (kt == qt) {
#pragma unroll
                for (int n = 0; n < 4; n++)
#pragma unroll
                    for (int r = 0; r < 4; r++)
                        if (n * 16 + mr > wid * 16 + quad * 4 + r) sv[n][r] = -1e30f;
            }
#pragma unroll
            for (int r = 0; r < 4; r++) {
                float rm = fmaxf(fmaxf(sv[0][r], sv[1][r]), fmaxf(sv[2][r], sv[3][r]));
                rm = fmaxf(rm, __shfl_xor(rm, 1));
                rm = fmaxf(rm, __shfl_xor(rm, 2));
                rm = fmaxf(rm, __shfl_xor(rm, 4));
                rm = fmaxf(rm, __shfl_xor(rm, 8));
                const float mn = fmaxf(mo[r], rm);
                const float al = __expf(mo[r] - mn);
                mo[r] = mn;
                float ls = 0.f;
                unsigned short* prow = Ps + (wid * 16 + quad * 4 + r) * KSTR + mr;
#pragma unroll
                for (int n = 0; n < 4; n++) {
                    const float p = __expf(sv[n][r] - mn);
                    const unsigned short pb = f2bf(p);
                    prow[n * 16] = pb;
                    ls += bf2f(pb);
                }
                ls += __shfl_xor(ls, 1);
                ls += __shfl_xor(ls, 2);
                ls += __shfl_xor(ls, 4);
                ls += __shfl_xor(ls, 8);
                lo[r] = lo[r] * al + ls;
#pragma unroll
                for (int d = 0; d < 4; d++) o[d][r] *= al;
            }

            // ---- O += P V (wave-private Ps strip; same-wave dep via lgkmcnt) ----
            {
                const unsigned short* pb = Ps + (wid * 16 + mr) * KSTR + quad * 8;
                short8 pa0 = *(const short8*)pb;
                short8 pa1 = *(const short8*)(pb + 32);
#pragma unroll
                for (int d = 0; d < 4; d++) {
                    const unsigned short* vb = Vs + (d * 16 + mr) * KSTR + quad * 8;
                    short8 vf0 = *(const short8*)vb;
                    short8 vf1 = *(const short8*)(vb + 32);
                    o[d] = __builtin_amdgcn_mfma_f32_16x16x32_bf16(pa0, vf0, o[d], 0, 0, 0);
                    o[d] = __builtin_amdgcn_mfma_f32_16x16x32_bf16(pa1, vf1, o[d], 0, 0, 0);
                }
            }
        }

        // ---- write O (C-layout: row quad*4+r, col d*16+mr) ----
#pragma unroll
        for (int r = 0; r < 4; r++) {
            const float inv = 1.0f / lo[r];
            const int qrow = qb + wid * 16 + quad * 4 + r;
            unsigned short* po = out + ((size_t)(qrow * 2 + b)) * H_DIM + nh * HDIM + mr;
#pragma unroll
            for (int d = 0; d < 4; d++) po[d * 16] = f2bf(o[d][r] * inv);
        }
    }
}

extern "C" void kernel_launch(void* const* d_in, const int* in_sizes, int n_in,
                              void* d_out, int out_size, void* d_ws, size_t ws_size,
                              hipStream_t stream) {
    const float* x      = (const float*)d_in[0];
    const float* ln1_w  = (const float*)d_in[1];
    const float* ln1_b  = (const float*)d_in[2];
    const float* w_qkv  = (const float*)d_in[3];
    const float* b_qkv  = (const float*)d_in[4];
    const float* w_proj = (const float*)d_in[5];
    const float* b_proj = (const float*)d_in[6];
    const float* ln2_w  = (const float*)d_in[7];
    const float* ln2_b  = (const float*)d_in[8];
    const float* w_fc1  = (const float*)d_in[9];
    const float* b_fc1  = (const float*)d_in[10];
    const float* w_fc2  = (const float*)d_in[11];
    const float* b_fc2  = (const float*)d_in[12];
    float* out = (float*)d_out;

    char* ws = (char*)d_ws;
    unsigned short* wqkv_bf  = (unsigned short*)(ws);                        // 6 MB
    unsigned short* wproj_bf = (unsigned short*)(ws + ((size_t)6 << 20));    // 2 MB
    unsigned short* wfc1_bf  = (unsigned short*)(ws + ((size_t)8 << 20));    // 8 MB
    unsigned short* wfc2_bf  = (unsigned short*)(ws + ((size_t)16 << 20));   // 8 MB
    unsigned short* ln_buf   = (unsigned short*)(ws + ((size_t)24 << 20));   // 8 MB
    unsigned short* qkv_bf   = (unsigned short*)(ws + ((size_t)32 << 20));   // 24 MB
    unsigned short* attn_bf  = (unsigned short*)(ws + ((size_t)56 << 20));   // 8 MB
    unsigned short* fc1_bf   = (unsigned short*)(ws + ((size_t)32 << 20));   // 32 MB (qkv/attn dead)

    cast_w<<<3072, 256, 0, stream>>>(w_qkv,  wqkv_bf,  3 * 1024 * 1024 / 4);
    cast_w<<<1024, 256, 0, stream>>>(w_proj, wproj_bf, 1024 * 1024 / 4);
    cast_w<<<4096, 256, 0, stream>>>(w_fc1,  wfc1_bf,  4 * 1024 * 1024 / 4);
    cast_w<<<4096, 256, 0, stream>>>(w_fc2,  wfc2_bf,  4 * 1024 * 1024 / 4);

    // 1) LN1 -> bf16
    ln_bf16<<<M_ROWS, 256, 0, stream>>>(x, ln1_w, ln1_b, ln_buf);
    // 2) qkv = ln1 @ w_qkv^T + b_qkv   [4096,3072] bf16
    gemm_mfma<0, true><<<dim3(24, 32), 256, 0, stream>>>(
        ln_buf, wqkv_bf, b_qkv, nullptr, qkv_bf, M_ROWS, 3072, 1024);
    // 3) MFMA flash attention -> bf16 [4096,1024]
    attn_mfma<<<dim3(16, 32), 256, 0, stream>>>(qkv_bf, attn_bf);
    // 4) x1 = x + attn @ w_proj^T + b_proj  -> d_out (fp32)
    gemm_mfma<1, false><<<dim3(8, 32), 256, 0, stream>>>(
        attn_bf, wproj_bf, b_proj, x, out, M_ROWS, 1024, 1024);
    // 5) LN2 -> bf16
    ln_bf16<<<M_ROWS, 256, 0, stream>>>(out, ln2_w, ln2_b, ln_buf);
    // 6) fc1 + gelu -> bf16 [4096,4096]
    gemm_mfma<2, true><<<dim3(32, 32), 256, 0, stream>>>(
        ln_buf, wfc1_bf, b_fc1, nullptr, fc1_bf, M_ROWS, 4096, 1024);
    // 7) out = x1 + fc1 @ w_fc2^T + b_fc2 (in-place residual)
    gemm_mfma<1, false><<<dim3(8, 32), 256, 0, stream>>>(
        fc1_bf, wfc2_bf, b_fc2, out, out, M_ROWS, 1024, 4096);
}

// Round 4
// 426.649 us; speedup vs baseline: 9.9001x; 1.0450x over previous
//
#include <hip/hip_runtime.h>
#include <math.h>

#define S_LEN 2048
#define B_SZ 2
#define NHEAD 16
#define HDIM 64
#define H_DIM 1024
#define M_ROWS (S_LEN * B_SZ)   // 4096
#define LN_EPS 1e-5f
#define KSTR 72                  // attn LDS row stride (shorts): 2-way banks = free

typedef __attribute__((ext_vector_type(4))) float f32x4;
typedef __attribute__((ext_vector_type(8))) short short8;
typedef __attribute__((ext_vector_type(8))) unsigned short u16x8;
typedef __attribute__((ext_vector_type(4))) unsigned short u16x4;
typedef __attribute__((ext_vector_type(2))) unsigned short u16x2;

__device__ __forceinline__ float bf2f(unsigned short u) {
    return __uint_as_float(((unsigned int)u) << 16);
}
__device__ __forceinline__ unsigned short f2bf(float f) {
    unsigned int u = __float_as_uint(f);
    return (unsigned short)((u + 0x7fffu + ((u >> 16) & 1u)) >> 16);
}
__device__ __forceinline__ void gld_lds16(const void* g, void* l) {
    __builtin_amdgcn_global_load_lds(
        (const __attribute__((address_space(1))) void*)g,
        (__attribute__((address_space(3))) void*)l, 16, 0, 0);
}

// ---------------- weight cast fp32 -> bf16 ----------------------------------
__global__ __launch_bounds__(256) void cast_w(const float* __restrict__ in,
                                              unsigned short* __restrict__ out,
                                              int n4) {
    const int i = blockIdx.x * 256 + threadIdx.x;
    if (i < n4) {
        f32x4 v = ((const f32x4*)in)[i];
        u16x4 o;
        o.x = f2bf(v.x); o.y = f2bf(v.y); o.z = f2bf(v.z); o.w = f2bf(v.w);
        ((u16x4*)out)[i] = o;
    }
}

// ---------------- LayerNorm row of 1024 -> bf16 -----------------------------
__global__ __launch_bounds__(256) void ln_bf16(const float* __restrict__ x,
                                               const float* __restrict__ w,
                                               const float* __restrict__ b,
                                               unsigned short* __restrict__ y) {
    const int m = blockIdx.x;
    const int tid = threadIdx.x;
    const float* row = x + (size_t)m * H_DIM;

    float4 v = ((const float4*)row)[tid];
    float s  = v.x + v.y + v.z + v.w;
    float ss = v.x * v.x + v.y * v.y + v.z * v.z + v.w * v.w;

    __shared__ float rs[4], rss[4], stats[2];
    const int wave = tid >> 6, lane = tid & 63;
    for (int off = 32; off; off >>= 1) {
        s  += __shfl_down(s, off);
        ss += __shfl_down(ss, off);
    }
    if (lane == 0) { rs[wave] = s; rss[wave] = ss; }
    __syncthreads();
    if (tid == 0) {
        float S = rs[0] + rs[1] + rs[2] + rs[3];
        float SS = rss[0] + rss[1] + rss[2] + rss[3];
        float mean = S * (1.0f / H_DIM);
        float var = SS * (1.0f / H_DIM) - mean * mean;
        stats[0] = mean;
        stats[1] = rsqrtf(var + LN_EPS);
    }
    __syncthreads();
    const float mean = stats[0], inv = stats[1];
    float4 wv = ((const float4*)w)[tid];
    float4 bv = ((const float4*)b)[tid];
    u16x4 o;
    o.x = f2bf((v.x - mean) * inv * wv.x + bv.x);
    o.y = f2bf((v.y - mean) * inv * wv.y + bv.y);
    o.z = f2bf((v.z - mean) * inv * wv.z + bv.z);
    o.w = f2bf((v.w - mean) * inv * wv.w + bv.w);
    ((u16x4*)(y + (size_t)m * H_DIM))[tid] = o;
}

// ---------------- bf16 MFMA GEMM, dbuf + XCD swizzle ------------------------
// C[M,N] = A[M,K] @ B[N,K]^T + bias. EPI: 0=bias, 1=+resid, 2=+gelu. 1D grid.
// Requires M % 1024 == 0 (mb divisible by 8).
template <int EPI, bool BF_OUT>
__global__ __launch_bounds__(256) void gemm_mfma(const unsigned short* __restrict__ A,
                                                 const unsigned short* __restrict__ B,
                                                 const float* __restrict__ bias,
                                                 const float* __restrict__ resid,
                                                 void* __restrict__ Cout,
                                                 int M, int N, int K) {
    __shared__ __attribute__((aligned(16))) unsigned short As[2][128 * 32];
    __shared__ __attribute__((aligned(16))) unsigned short Bs[2][128 * 32];

    const int tid = threadIdx.x;
    const int wid = tid >> 6;
    const int ln  = tid & 63;
    const int quad = ln >> 4;
    const int mr   = ln & 15;
    const int wm = (wid >> 1) * 64;
    const int wn = (wid & 1) * 64;

    // XCD-aware swizzle: xcd = id&7 (round-robin dispatch heuristic).
    // Each XCD owns a 4-m-tile stripe (A resident in its L2); consecutive
    // locals share an n-tile (B-tile temporal reuse within the XCD).
    const int mb = M >> 7;
    const int stripe = mb >> 3;               // 4 for M=4096
    const int xcd = blockIdx.x & 7;
    const int local = blockIdx.x >> 3;
    const int m0 = (xcd * stripe + (local % stripe)) << 7;
    const int n0 = (local / stripe) << 7;

    const int c  = wid * 64 + ln;
    const int r0 = c >> 2;
    const int k0 = (c & 3) * 8;
    const unsigned short* gA0 = A + (size_t)(m0 + r0) * K + k0;
    const unsigned short* gA1 = A + (size_t)(m0 + 64 + r0) * K + k0;
    const unsigned short* gB0 = B + (size_t)(n0 + r0) * K + k0;
    const unsigned short* gB1 = B + (size_t)(n0 + 64 + r0) * K + k0;
    const int lo0 = wid * 512;
    const int lo1 = 2048 + wid * 512;

    const f32x4 zero = {0.f, 0.f, 0.f, 0.f};
    f32x4 acc[4][4];
#pragma unroll
    for (int i = 0; i < 4; i++)
#pragma unroll
        for (int j = 0; j < 4; j++) acc[i][j] = zero;

    const int nt = K >> 5;
    // prefetch tile 0 into buffer 0
    gld_lds16(gA0, As[0] + lo0);
    gld_lds16(gA1, As[0] + lo1);
    gld_lds16(gB0, Bs[0] + lo0);
    gld_lds16(gB1, Bs[0] + lo1);

    for (int kt = 0; kt < nt; kt++) {
        __syncthreads();   // drains tile-kt staging; protects buf overwrite
        const int nxt = kt + 1;
        if (nxt < nt) {
            const int nb_ = nxt & 1;
            const int koff = nxt * 32;
            gld_lds16(gA0 + koff, As[nb_] + lo0);
            gld_lds16(gA1 + koff, As[nb_] + lo1);
            gld_lds16(gB0 + koff, Bs[nb_] + lo0);
            gld_lds16(gB1 + koff, Bs[nb_] + lo1);
        }
        const unsigned short* as = As[kt & 1];
        const unsigned short* bs = Bs[kt & 1];
        short8 af[4], bfr[4];
#pragma unroll
        for (int i = 0; i < 4; i++)
            af[i] = *(const short8*)(as + (wm + i * 16 + mr) * 32 + quad * 8);
#pragma unroll
        for (int j = 0; j < 4; j++)
            bfr[j] = *(const short8*)(bs + (wn + j * 16 + mr) * 32 + quad * 8);
#pragma unroll
        for (int i = 0; i < 4; i++)
#pragma unroll
            for (int j = 0; j < 4; j++)
                acc[i][j] = __builtin_amdgcn_mfma_f32_16x16x32_bf16(af[i], bfr[j], acc[i][j], 0, 0, 0);
    }

#pragma unroll
    for (int j = 0; j < 4; j++) {
        const int n = n0 + wn + j * 16 + mr;
        const float bv = bias[n];
#pragma unroll
        for (int i = 0; i < 4; i++) {
#pragma unroll
            for (int r = 0; r < 4; r++) {
                const int m = m0 + wm + i * 16 + quad * 4 + r;
                float v = acc[i][j][r] + bv;
                if (EPI == 1) v += resid[(size_t)m * N + n];
                if (EPI == 2) {
                    const float t = v;
                    v = 0.5f * t * (1.0f + tanhf(0.7978845608f * (t + 0.044715f * t * t * t)));
                }
                if (BF_OUT) ((unsigned short*)Cout)[(size_t)m * N + n] = f2bf(v);
                else        ((float*)Cout)[(size_t)m * N + n] = v;
            }
        }
    }
}

// ---------------- MFMA flash attention --------------------------------------
__global__ __launch_bounds__(256) void attn_mfma(const unsigned short* __restrict__ qkv,
                                                 unsigned short* __restrict__ out) {
    __shared__ __attribute__((aligned(16))) unsigned short Ks[64 * KSTR];
    __shared__ __attribute__((aligned(16))) unsigned short Vs[64 * KSTR];
    __shared__ __attribute__((aligned(16))) unsigned short Ps[64 * KSTR];

    const int tid = threadIdx.x;
    const int wid = tid >> 6;
    const int ln  = tid & 63;
    const int quad = ln >> 4;
    const int mr   = ln & 15;
    const int pa = blockIdx.x;                 // 0..15
    const int b  = blockIdx.y >> 4;
    const int nh = blockIdx.y & 15;
    const size_t chan = (size_t)nh * 192;

    const int ksr = tid >> 2, ksc = tid & 3;
    const int vt0 = (tid & 31) * 2, vd0 = (tid >> 5) * 8;

#pragma unroll
    for (int half = 0; half < 2; half++) {
        const int qt = half ? (31 - pa) : pa;
        const int qb = qt * 64;

        short8 qf0, qf1;
        {
            const int qrow = qb + wid * 16 + mr;
            const unsigned short* gq = qkv + ((size_t)(qrow * 2 + b)) * 3072 + chan + quad * 8;
            qf0 = *(const short8*)gq;
            qf1 = *(const short8*)(gq + 32);
        }

        const f32x4 zero = {0.f, 0.f, 0.f, 0.f};
        f32x4 o[4];
        float mo[4], lo[4];
#pragma unroll
        for (int d = 0; d < 4; d++) o[d] = zero;
#pragma unroll
        for (int r = 0; r < 4; r++) { mo[r] = -1e30f; lo[r] = 0.f; }

        for (int kt = 0; kt <= qt; kt++) {
            const int ktb = kt * 64;
            __syncthreads();
            {
                const unsigned short* gk =
                    qkv + ((size_t)((ktb + ksr) * 2 + b)) * 3072 + chan + 64 + ksc * 16;
                u16x8 k0 = *(const u16x8*)gk;
                u16x8 k1 = *(const u16x8*)(gk + 8);
                *(u16x8*)(Ks + ksr * KSTR + ksc * 16) = k0;
                *(u16x8*)(Ks + ksr * KSTR + ksc * 16 + 8) = k1;
            }
            {
                const unsigned short* gv =
                    qkv + ((size_t)((ktb + vt0) * 2 + b)) * 3072 + chan + 128 + vd0;
                u16x8 v0 = *(const u16x8*)gv;
                u16x8 v1 = *(const u16x8*)(gv + 6144);
#pragma unroll
                for (int j = 0; j < 8; j++) {
                    u16x2 pr; pr.x = v0[j]; pr.y = v1[j];
                    *(u16x2*)(Vs + (vd0 + j) * KSTR + vt0) = pr;
                }
            }
            __syncthreads();

            f32x4 sacc[4];
#pragma unroll
            for (int n = 0; n < 4; n++) {
                sacc[n] = zero;
                const unsigned short* kb = Ks + (n * 16 + mr) * KSTR + quad * 8;
                short8 kfr0 = *(const short8*)kb;
                short8 kfr1 = *(const short8*)(kb + 32);
                sacc[n] = __builtin_amdgcn_mfma_f32_16x16x32_bf16(qf0, kfr0, sacc[n], 0, 0, 0);
                sacc[n] = __builtin_amdgcn_mfma_f32_16x16x32_bf16(qf1, kfr1, sacc[n], 0, 0, 0);
            }

            float sv[4][4];
#pragma unroll
            for (int n = 0; n < 4; n++)
#pragma unroll
                for (int r = 0; r < 4; r++) sv[n][r] = sacc[n][r] * 0.125f;
            if (kt == qt) {
#pragma unroll
                for (int n = 0; n < 4; n++)
#pragma unroll
                    for (int r = 0; r < 4; r++)
                        if (n * 16 + mr > wid * 16 + quad * 4 + r) sv[n][r] = -1e30f;
            }
#pragma unroll
            for (int r = 0; r < 4; r++) {
                float rm = fmaxf(fmaxf(sv[0][r], sv[1][r]), fmaxf(sv[2][r], sv[3][r]));
                rm = fmaxf(rm, __shfl_xor(rm, 1));
                rm = fmaxf(rm, __shfl_xor(rm, 2));
                rm = fmaxf(rm, __shfl_xor(rm, 4));
                rm = fmaxf(rm, __shfl_xor(rm, 8));
                const float mn = fmaxf(mo[r], rm);
                const float al = __expf(mo[r] - mn);
                mo[r] = mn;
                float ls = 0.f;
                unsigned short* prow = Ps + (wid * 16 + quad * 4 + r) * KSTR + mr;
#pragma unroll
                for (int n = 0; n < 4; n++) {
                    const float p = __expf(sv[n][r] - mn);
                    const unsigned short pb = f2bf(p);
                    prow[n * 16] = pb;
                    ls += bf2f(pb);
                }
                ls += __shfl_xor(ls, 1);
                ls += __shfl_xor(ls, 2);
                ls += __shfl_xor(ls, 4);
                ls += __shfl_xor(ls, 8);
                lo[r] = lo[r] * al + ls;
#pragma unroll
                for (int d = 0; d < 4; d++) o[d][r] *= al;
            }

            {
                const unsigned short* pb = Ps + (wid * 16 + mr) * KSTR + quad * 8;
                short8 pa0 = *(const short8*)pb;
                short8 pa1 = *(const short8*)(pb + 32);
#pragma unroll
                for (int d = 0; d < 4; d++) {
                    const unsigned short* vb = Vs + (d * 16 + mr) * KSTR + quad * 8;
                    short8 vf0 = *(const short8*)vb;
                    short8 vf1 = *(const short8*)(vb + 32);
                    o[d] = __builtin_amdgcn_mfma_f32_16x16x32_bf16(pa0, vf0, o[d], 0, 0, 0);
                    o[d] = __builtin_amdgcn_mfma_f32_16x16x32_bf16(pa1, vf1, o[d], 0, 0, 0);
                }
            }
        }

#pragma unroll
        for (int r = 0; r < 4; r++) {
            const float inv = 1.0f / lo[r];
            const int qrow = qb + wid * 16 + quad * 4 + r;
            unsigned short* po = out + ((size_t)(qrow * 2 + b)) * H_DIM + nh * HDIM + mr;
#pragma unroll
            for (int d = 0; d < 4; d++) po[d * 16] = f2bf(o[d][r] * inv);
        }
    }
}

extern "C" void kernel_launch(void* const* d_in, const int* in_sizes, int n_in,
                              void* d_out, int out_size, void* d_ws, size_t ws_size,
                              hipStream_t stream) {
    const float* x      = (const float*)d_in[0];
    const float* ln1_w  = (const float*)d_in[1];
    const float* ln1_b  = (const float*)d_in[2];
    const float* w_qkv  = (const float*)d_in[3];
    const float* b_qkv  = (const float*)d_in[4];
    const float* w_proj = (const float*)d_in[5];
    const float* b_proj = (const float*)d_in[6];
    const float* ln2_w  = (const float*)d_in[7];
    const float* ln2_b  = (const float*)d_in[8];
    const float* w_fc1  = (const float*)d_in[9];
    const float* b_fc1  = (const float*)d_in[10];
    const float* w_fc2  = (const float*)d_in[11];
    const float* b_fc2  = (const float*)d_in[12];
    float* out = (float*)d_out;

    char* ws = (char*)d_ws;
    unsigned short* wqkv_bf  = (unsigned short*)(ws);                        // 6 MB
    unsigned short* wproj_bf = (unsigned short*)(ws + ((size_t)6 << 20));    // 2 MB
    unsigned short* wfc1_bf  = (unsigned short*)(ws + ((size_t)8 << 20));    // 8 MB
    unsigned short* wfc2_bf  = (unsigned short*)(ws + ((size_t)16 << 20));   // 8 MB
    unsigned short* ln_buf   = (unsigned short*)(ws + ((size_t)24 << 20));   // 8 MB
    unsigned short* qkv_bf   = (unsigned short*)(ws + ((size_t)32 << 20));   // 24 MB
    unsigned short* attn_bf  = (unsigned short*)(ws + ((size_t)56 << 20));   // 8 MB
    unsigned short* fc1_bf   = (unsigned short*)(ws + ((size_t)32 << 20));   // 32 MB (qkv/attn dead)

    cast_w<<<3072, 256, 0, stream>>>(w_qkv,  wqkv_bf,  3 * 1024 * 1024 / 4);
    cast_w<<<1024, 256, 0, stream>>>(w_proj, wproj_bf, 1024 * 1024 / 4);
    cast_w<<<4096, 256, 0, stream>>>(w_fc1,  wfc1_bf,  4 * 1024 * 1024 / 4);
    cast_w<<<4096, 256, 0, stream>>>(w_fc2,  wfc2_bf,  4 * 1024 * 1024 / 4);

    // 1) LN1 -> bf16
    ln_bf16<<<M_ROWS, 256, 0, stream>>>(x, ln1_w, ln1_b, ln_buf);
    // 2) qkv = ln1 @ w_qkv^T + b_qkv   [4096,3072] bf16   (768 blocks)
    gemm_mfma<0, true><<<768, 256, 0, stream>>>(
        ln_buf, wqkv_bf, b_qkv, nullptr, qkv_bf, M_ROWS, 3072, 1024);
    // 3) MFMA flash attention -> bf16 [4096,1024]
    attn_mfma<<<dim3(16, 32), 256, 0, stream>>>(qkv_bf, attn_bf);
    // 4) x1 = x + attn @ w_proj^T + b_proj  -> d_out (fp32)   (256 blocks)
    gemm_mfma<1, false><<<256, 256, 0, stream>>>(
        attn_bf, wproj_bf, b_proj, x, out, M_ROWS, 1024, 1024);
    // 5) LN2 -> bf16
    ln_bf16<<<M_ROWS, 256, 0, stream>>>(out, ln2_w, ln2_b, ln_buf);
    // 6) fc1 + gelu -> bf16 [4096,4096]   (1024 blocks)
    gemm_mfma<2, true><<<1024, 256, 0, stream>>>(
        ln_buf, wfc1_bf, b_fc1, nullptr, fc1_bf, M_ROWS, 4096, 1024);
    // 7) out = x1 + fc1 @ w_fc2^T + b_fc2 (in-place residual)   (256 blocks)
    gemm_mfma<1, false><<<256, 256, 0, stream>>>(
        fc1_bf, wfc2_bf, b_fc2, out, out, M_ROWS, 1024, 4096);
}

// Round 5
// 407.329 us; speedup vs baseline: 10.3696x; 1.0474x over previous
//
#include <hip/hip_runtime.h>
#include <math.h>

#define S_LEN 2048
#define B_SZ 2
#define NHEAD 16
#define HDIM 64
#define H_DIM 1024
#define M_ROWS (S_LEN * B_SZ)   // 4096
#define LN_EPS 1e-5f
#define KSTR 72                  // attn LDS row stride (shorts): 2-way banks = free
#define SCL 0.18033688011112042f // 0.125 * log2(e)

typedef __attribute__((ext_vector_type(4))) float f32x4;
typedef __attribute__((ext_vector_type(8))) short short8;
typedef __attribute__((ext_vector_type(8))) unsigned short u16x8;
typedef __attribute__((ext_vector_type(4))) unsigned short u16x4;
typedef __attribute__((ext_vector_type(2))) unsigned short u16x2;

__device__ __forceinline__ float bf2f(unsigned short u) {
    return __uint_as_float(((unsigned int)u) << 16);
}
__device__ __forceinline__ unsigned short f2bf(float f) {
    unsigned int u = __float_as_uint(f);
    return (unsigned short)((u + 0x7fffu + ((u >> 16) & 1u)) >> 16);
}
__device__ __forceinline__ void gld_lds16(const void* g, void* l) {
    __builtin_amdgcn_global_load_lds(
        (const __attribute__((address_space(1))) void*)g,
        (__attribute__((address_space(3))) void*)l, 16, 0, 0);
}

// ---------------- weight cast fp32 -> bf16 ----------------------------------
__global__ __launch_bounds__(256) void cast_w(const float* __restrict__ in,
                                              unsigned short* __restrict__ out,
                                              int n4) {
    const int i = blockIdx.x * 256 + threadIdx.x;
    if (i < n4) {
        f32x4 v = ((const f32x4*)in)[i];
        u16x4 o;
        o.x = f2bf(v.x); o.y = f2bf(v.y); o.z = f2bf(v.z); o.w = f2bf(v.w);
        ((u16x4*)out)[i] = o;
    }
}

// ---------------- LayerNorm row of 1024 -> bf16 -----------------------------
__global__ __launch_bounds__(256) void ln_bf16(const float* __restrict__ x,
                                               const float* __restrict__ w,
                                               const float* __restrict__ b,
                                               unsigned short* __restrict__ y) {
    const int m = blockIdx.x;
    const int tid = threadIdx.x;
    const float* row = x + (size_t)m * H_DIM;

    float4 v = ((const float4*)row)[tid];
    float s  = v.x + v.y + v.z + v.w;
    float ss = v.x * v.x + v.y * v.y + v.z * v.z + v.w * v.w;

    __shared__ float rs[4], rss[4], stats[2];
    const int wave = tid >> 6, lane = tid & 63;
    for (int off = 32; off; off >>= 1) {
        s  += __shfl_down(s, off);
        ss += __shfl_down(ss, off);
    }
    if (lane == 0) { rs[wave] = s; rss[wave] = ss; }
    __syncthreads();
    if (tid == 0) {
        float S = rs[0] + rs[1] + rs[2] + rs[3];
        float SS = rss[0] + rss[1] + rss[2] + rss[3];
        float mean = S * (1.0f / H_DIM);
        float var = SS * (1.0f / H_DIM) - mean * mean;
        stats[0] = mean;
        stats[1] = rsqrtf(var + LN_EPS);
    }
    __syncthreads();
    const float mean = stats[0], inv = stats[1];
    float4 wv = ((const float4*)w)[tid];
    float4 bv = ((const float4*)b)[tid];
    u16x4 o;
    o.x = f2bf((v.x - mean) * inv * wv.x + bv.x);
    o.y = f2bf((v.y - mean) * inv * wv.y + bv.y);
    o.z = f2bf((v.z - mean) * inv * wv.z + bv.z);
    o.w = f2bf((v.w - mean) * inv * wv.w + bv.w);
    ((u16x4*)(y + (size_t)m * H_DIM))[tid] = o;
}

// ---------------- bf16 MFMA GEMM, dbuf + XCD swizzle ------------------------
// C[M,N] = A[M,K] @ B[N,K]^T + bias. EPI: 0=bias, 1=+resid, 2=+gelu. 1D grid.
template <int EPI, bool BF_OUT>
__global__ __launch_bounds__(256) void gemm_mfma(const unsigned short* __restrict__ A,
                                                 const unsigned short* __restrict__ B,
                                                 const float* __restrict__ bias,
                                                 const float* __restrict__ resid,
                                                 void* __restrict__ Cout,
                                                 int M, int N, int K) {
    __shared__ __attribute__((aligned(16))) unsigned short As[2][128 * 32];
    __shared__ __attribute__((aligned(16))) unsigned short Bs[2][128 * 32];

    const int tid = threadIdx.x;
    const int wid = tid >> 6;
    const int ln  = tid & 63;
    const int quad = ln >> 4;
    const int mr   = ln & 15;
    const int wm = (wid >> 1) * 64;
    const int wn = (wid & 1) * 64;

    const int mb = M >> 7;
    const int stripe = mb >> 3;               // 4 for M=4096
    const int xcd = blockIdx.x & 7;
    const int local = blockIdx.x >> 3;
    const int m0 = (xcd * stripe + (local % stripe)) << 7;
    const int n0 = (local / stripe) << 7;

    const int c  = wid * 64 + ln;
    const int r0 = c >> 2;
    const int k0 = (c & 3) * 8;
    const unsigned short* gA0 = A + (size_t)(m0 + r0) * K + k0;
    const unsigned short* gA1 = A + (size_t)(m0 + 64 + r0) * K + k0;
    const unsigned short* gB0 = B + (size_t)(n0 + r0) * K + k0;
    const unsigned short* gB1 = B + (size_t)(n0 + 64 + r0) * K + k0;
    const int lo0 = wid * 512;
    const int lo1 = 2048 + wid * 512;

    const f32x4 zero = {0.f, 0.f, 0.f, 0.f};
    f32x4 acc[4][4];
#pragma unroll
    for (int i = 0; i < 4; i++)
#pragma unroll
        for (int j = 0; j < 4; j++) acc[i][j] = zero;

    const int nt = K >> 5;
    gld_lds16(gA0, As[0] + lo0);
    gld_lds16(gA1, As[0] + lo1);
    gld_lds16(gB0, Bs[0] + lo0);
    gld_lds16(gB1, Bs[0] + lo1);

    for (int kt = 0; kt < nt; kt++) {
        __syncthreads();
        const int nxt = kt + 1;
        if (nxt < nt) {
            const int nb_ = nxt & 1;
            const int koff = nxt * 32;
            gld_lds16(gA0 + koff, As[nb_] + lo0);
            gld_lds16(gA1 + koff, As[nb_] + lo1);
            gld_lds16(gB0 + koff, Bs[nb_] + lo0);
            gld_lds16(gB1 + koff, Bs[nb_] + lo1);
        }
        const unsigned short* as = As[kt & 1];
        const unsigned short* bs = Bs[kt & 1];
        short8 af[4], bfr[4];
#pragma unroll
        for (int i = 0; i < 4; i++)
            af[i] = *(const short8*)(as + (wm + i * 16 + mr) * 32 + quad * 8);
#pragma unroll
        for (int j = 0; j < 4; j++)
            bfr[j] = *(const short8*)(bs + (wn + j * 16 + mr) * 32 + quad * 8);
#pragma unroll
        for (int i = 0; i < 4; i++)
#pragma unroll
            for (int j = 0; j < 4; j++)
                acc[i][j] = __builtin_amdgcn_mfma_f32_16x16x32_bf16(af[i], bfr[j], acc[i][j], 0, 0, 0);
    }

#pragma unroll
    for (int j = 0; j < 4; j++) {
        const int n = n0 + wn + j * 16 + mr;
        const float bv = bias[n];
#pragma unroll
        for (int i = 0; i < 4; i++) {
#pragma unroll
            for (int r = 0; r < 4; r++) {
                const int m = m0 + wm + i * 16 + quad * 4 + r;
                float v = acc[i][j][r] + bv;
                if (EPI == 1) v += resid[(size_t)m * N + n];
                if (EPI == 2) {
                    const float t = v;
                    v = 0.5f * t * (1.0f + tanhf(0.7978845608f * (t + 0.044715f * t * t * t)));
                }
                if (BF_OUT) ((unsigned short*)Cout)[(size_t)m * N + n] = f2bf(v);
                else        ((float*)Cout)[(size_t)m * N + n] = v;
            }
        }
    }
}

// ---------------- MFMA flash attention, XCD-local + reg-prefetch ------------
// Grid: 512 blocks, 1-D. id&7 selects XCD stripe; each XCD owns 4 (b,nh)
// pairs (K/V working set 2 MB < 4 MB L2). Block does q-tiles (pa, 31-pa).
__global__ __launch_bounds__(256) void attn_mfma(const unsigned short* __restrict__ qkv,
                                                 unsigned short* __restrict__ out) {
    __shared__ __attribute__((aligned(16))) unsigned short Ks[64 * KSTR];
    __shared__ __attribute__((aligned(16))) unsigned short Vs[64 * KSTR];
    __shared__ __attribute__((aligned(16))) unsigned short Ps[64 * KSTR];

    const int tid = threadIdx.x;
    const int wid = tid >> 6;
    const int ln  = tid & 63;
    const int quad = ln >> 4;
    const int mr   = ln & 15;

    const int id = blockIdx.x;                 // 0..511
    const int local = id >> 3;                 // 0..63
    const int bh = (id & 7) * 4 + (local >> 4);
    const int pa = local & 15;
    const int b  = bh >> 4;
    const int nh = bh & 15;
    const size_t chan = (size_t)nh * 192;

    const int ksr = tid >> 2, ksc = tid & 3;
    const int vt0 = (tid & 31) * 2, vd0 = (tid >> 5) * 8;

    u16x8 kp0, kp1, vp0, vp1;   // prefetch registers

#pragma unroll
    for (int half = 0; half < 2; half++) {
        const int qt = half ? (31 - pa) : pa;
        const int qb = qt * 64;

        short8 qf0, qf1;
        {
            const int qrow = qb + wid * 16 + mr;
            const unsigned short* gq = qkv + ((size_t)(qrow * 2 + b)) * 3072 + chan + quad * 8;
            qf0 = *(const short8*)gq;
            qf1 = *(const short8*)(gq + 32);
        }

        const f32x4 zero = {0.f, 0.f, 0.f, 0.f};
        f32x4 o[4];
        float mo[4], lo[4];
#pragma unroll
        for (int d = 0; d < 4; d++) o[d] = zero;
#pragma unroll
        for (int r = 0; r < 4; r++) { mo[r] = -3.0e38f; lo[r] = 0.f; }

        // prefetch k-tile 0
        {
            const unsigned short* gk = qkv + ((size_t)(ksr * 2 + b)) * 3072 + chan + 64 + ksc * 16;
            kp0 = *(const u16x8*)gk;
            kp1 = *(const u16x8*)(gk + 8);
            const unsigned short* gv = qkv + ((size_t)(vt0 * 2 + b)) * 3072 + chan + 128 + vd0;
            vp0 = *(const u16x8*)gv;
            vp1 = *(const u16x8*)(gv + 6144);
        }

        for (int kt = 0; kt <= qt; kt++) {
            __syncthreads();   // prev iter's Ks/Vs reads done
            // commit prefetched K/V to LDS
            *(u16x8*)(Ks + ksr * KSTR + ksc * 16) = kp0;
            *(u16x8*)(Ks + ksr * KSTR + ksc * 16 + 8) = kp1;
#pragma unroll
            for (int j = 0; j < 8; j++) {
                u16x2 pr; pr.x = vp0[j]; pr.y = vp1[j];
                *(u16x2*)(Vs + (vd0 + j) * KSTR + vt0) = pr;
            }
            // prefetch next tile (overlaps with this tile's compute)
            if (kt < qt) {
                const int nb = (kt + 1) * 64;
                const unsigned short* gk =
                    qkv + ((size_t)((nb + ksr) * 2 + b)) * 3072 + chan + 64 + ksc * 16;
                kp0 = *(const u16x8*)gk;
                kp1 = *(const u16x8*)(gk + 8);
                const unsigned short* gv =
                    qkv + ((size_t)((nb + vt0) * 2 + b)) * 3072 + chan + 128 + vd0;
                vp0 = *(const u16x8*)gv;
                vp1 = *(const u16x8*)(gv + 6144);
            }
            __syncthreads();   // staging visible

            // ---- S = Q K^T (raw scores; scale folded into exp2) ----
            f32x4 sacc[4];
#pragma unroll
            for (int n = 0; n < 4; n++) {
                sacc[n] = zero;
                const unsigned short* kb = Ks + (n * 16 + mr) * KSTR + quad * 8;
                short8 kfr0 = *(const short8*)kb;
                short8 kfr1 = *(const short8*)(kb + 32);
                sacc[n] = __builtin_amdgcn_mfma_f32_16x16x32_bf16(qf0, kfr0, sacc[n], 0, 0, 0);
                sacc[n] = __builtin_amdgcn_mfma_f32_16x16x32_bf16(qf1, kfr1, sacc[n], 0, 0, 0);
            }
            if (kt == qt) {
#pragma unroll
                for (int n = 0; n < 4; n++)
#pragma unroll
                    for (int r = 0; r < 4; r++)
                        if (n * 16 + mr > wid * 16 + quad * 4 + r) sacc[n][r] = -3.0e38f;
            }

            // ---- online softmax (exp2 domain, deferred lane-sum) ----
#pragma unroll
            for (int r = 0; r < 4; r++) {
                float rm = fmaxf(fmaxf(sacc[0][r], sacc[1][r]), fmaxf(sacc[2][r], sacc[3][r]));
                rm = fmaxf(rm, __shfl_xor(rm, 1));
                rm = fmaxf(rm, __shfl_xor(rm, 2));
                rm = fmaxf(rm, __shfl_xor(rm, 4));
                rm = fmaxf(rm, __shfl_xor(rm, 8));
                const float mn = fmaxf(mo[r], rm);
                const float al = exp2f((mo[r] - mn) * SCL);
                mo[r] = mn;
                const float off = -mn * SCL;
                float ps = 0.f;
                unsigned short* prow = Ps + (wid * 16 + quad * 4 + r) * KSTR + mr;
#pragma unroll
                for (int n = 0; n < 4; n++) {
                    const float p = exp2f(fmaf(sacc[n][r], SCL, off));
                    const unsigned short pb = (unsigned short)(__float_as_uint(p) >> 16);
                    prow[n * 16] = pb;
                    ps += bf2f(pb);
                }
                lo[r] = lo[r] * al + ps;   // per-lane partial; reduced in epilogue
#pragma unroll
                for (int d = 0; d < 4; d++) o[d][r] *= al;
            }

            // ---- O += P V ----
            {
                const unsigned short* pb = Ps + (wid * 16 + mr) * KSTR + quad * 8;
                short8 pa0 = *(const short8*)pb;
                short8 pa1 = *(const short8*)(pb + 32);
#pragma unroll
                for (int d = 0; d < 4; d++) {
                    const unsigned short* vb = Vs + (d * 16 + mr) * KSTR + quad * 8;
                    short8 vf0 = *(const short8*)vb;
                    short8 vf1 = *(const short8*)(vb + 32);
                    o[d] = __builtin_amdgcn_mfma_f32_16x16x32_bf16(pa0, vf0, o[d], 0, 0, 0);
                    o[d] = __builtin_amdgcn_mfma_f32_16x16x32_bf16(pa1, vf1, o[d], 0, 0, 0);
                }
            }
        }

        // ---- epilogue: reduce l across the 16-lane row group, write O ----
#pragma unroll
        for (int r = 0; r < 4; r++) {
            float ls = lo[r];
            ls += __shfl_xor(ls, 1);
            ls += __shfl_xor(ls, 2);
            ls += __shfl_xor(ls, 4);
            ls += __shfl_xor(ls, 8);
            const float inv = 1.0f / ls;
            const int qrow = qb + wid * 16 + quad * 4 + r;
            unsigned short* po = out + ((size_t)(qrow * 2 + b)) * H_DIM + nh * HDIM + mr;
#pragma unroll
            for (int d = 0; d < 4; d++) po[d * 16] = f2bf(o[d][r] * inv);
        }
    }
}

extern "C" void kernel_launch(void* const* d_in, const int* in_sizes, int n_in,
                              void* d_out, int out_size, void* d_ws, size_t ws_size,
                              hipStream_t stream) {
    const float* x      = (const float*)d_in[0];
    const float* ln1_w  = (const float*)d_in[1];
    const float* ln1_b  = (const float*)d_in[2];
    const float* w_qkv  = (const float*)d_in[3];
    const float* b_qkv  = (const float*)d_in[4];
    const float* w_proj = (const float*)d_in[5];
    const float* b_proj = (const float*)d_in[6];
    const float* ln2_w  = (const float*)d_in[7];
    const float* ln2_b  = (const float*)d_in[8];
    const float* w_fc1  = (const float*)d_in[9];
    const float* b_fc1  = (const float*)d_in[10];
    const float* w_fc2  = (const float*)d_in[11];
    const float* b_fc2  = (const float*)d_in[12];
    float* out = (float*)d_out;

    char* ws = (char*)d_ws;
    unsigned short* wqkv_bf  = (unsigned short*)(ws);                        // 6 MB
    unsigned short* wproj_bf = (unsigned short*)(ws + ((size_t)6 << 20));    // 2 MB
    unsigned short* wfc1_bf  = (unsigned short*)(ws + ((size_t)8 << 20));    // 8 MB
    unsigned short* wfc2_bf  = (unsigned short*)(ws + ((size_t)16 << 20));   // 8 MB
    unsigned short* ln_buf   = (unsigned short*)(ws + ((size_t)24 << 20));   // 8 MB
    unsigned short* qkv_bf   = (unsigned short*)(ws + ((size_t)32 << 20));   // 24 MB
    unsigned short* attn_bf  = (unsigned short*)(ws + ((size_t)56 << 20));   // 8 MB
    unsigned short* fc1_bf   = (unsigned short*)(ws + ((size_t)32 << 20));   // 32 MB (qkv/attn dead)

    cast_w<<<3072, 256, 0, stream>>>(w_qkv,  wqkv_bf,  3 * 1024 * 1024 / 4);
    cast_w<<<1024, 256, 0, stream>>>(w_proj, wproj_bf, 1024 * 1024 / 4);
    cast_w<<<4096, 256, 0, stream>>>(w_fc1,  wfc1_bf,  4 * 1024 * 1024 / 4);
    cast_w<<<4096, 256, 0, stream>>>(w_fc2,  wfc2_bf,  4 * 1024 * 1024 / 4);

    // 1) LN1 -> bf16
    ln_bf16<<<M_ROWS, 256, 0, stream>>>(x, ln1_w, ln1_b, ln_buf);
    // 2) qkv = ln1 @ w_qkv^T + b_qkv   [4096,3072] bf16   (768 blocks)
    gemm_mfma<0, true><<<768, 256, 0, stream>>>(
        ln_buf, wqkv_bf, b_qkv, nullptr, qkv_bf, M_ROWS, 3072, 1024);
    // 3) MFMA flash attention -> bf16 [4096,1024]   (512 blocks, XCD-local)
    attn_mfma<<<512, 256, 0, stream>>>(qkv_bf, attn_bf);
    // 4) x1 = x + attn @ w_proj^T + b_proj  -> d_out (fp32)   (256 blocks)
    gemm_mfma<1, false><<<256, 256, 0, stream>>>(
        attn_bf, wproj_bf, b_proj, x, out, M_ROWS, 1024, 1024);
    // 5) LN2 -> bf16
    ln_bf16<<<M_ROWS, 256, 0, stream>>>(out, ln2_w, ln2_b, ln_buf);
    // 6) fc1 + gelu -> bf16 [4096,4096]   (1024 blocks)
    gemm_mfma<2, true><<<1024, 256, 0, stream>>>(
        ln_buf, wfc1_bf, b_fc1, nullptr, fc1_bf, M_ROWS, 4096, 1024);
    // 7) out = x1 + fc1 @ w_fc2^T + b_fc2 (in-place residual)   (256 blocks)
    gemm_mfma<1, false><<<256, 256, 0, stream>>>(
        fc1_bf, wfc2_bf, b_fc2, out, out, M_ROWS, 1024, 4096);
}